// Round 15
// baseline (508.509 us; speedup 1.0000x reference)
//
#include <hip/hip_runtime.h>
#include <hip/hip_bf16.h>
#include <math.h>

// Problem constants
#define V_  32000
#define D_  512
#define DFF_ 2048
#define L_  4
#define H_  8
#define N_  64
#define K_  8
#define NB_ 32
#define R_  64
#define B_  2
#define S_  512
#define T_  1024   // B*S
#define DH_ 64

typedef short bhalf8 __attribute__((ext_vector_type(8)));
typedef float floatx4 __attribute__((ext_vector_type(4)));

#define GLOAD16(gp, lp) __builtin_amdgcn_global_load_lds( \
    (const __attribute__((address_space(1))) void*)(gp), \
    (__attribute__((address_space(3))) void*)(lp), 16, 0, 0)

__device__ __forceinline__ float gelu_f(float v) {
    return 0.5f * v * (1.0f + erff(v * 0.70710678118654752f));
}

__device__ __forceinline__ unsigned pk2(float a, float b) {
    unsigned ua = (unsigned)__bfloat16_as_ushort(__float2bfloat16(a));
    unsigned ub = (unsigned)__bfloat16_as_ushort(__float2bfloat16(b));
    return ua | (ub << 16);
}

// ------------------------------------------------------------- GEMM core
// C[M,N] = A[M,K] @ Bt[N,K]^T (+bias). bf16, BK=64, XOR-swizzle u^=row&7.
// PIPE=0: classic double-buffer (arena 2*(BM+BN)*64 shorts).
// PIPE=1: 3-buffer counted-vmcnt pipeline (arena 3*(BM+BN)*64 shorts) —
//         one stage (4 loads) stays in flight across each barrier.
// EPI: 0=f32, 1=bf16, 2=bf16 gelu, 3=xf, 4=f32 +=, 5=bf16+Vt scatter,
//      6=f32 atomic, 7=f32 two-half LDS-staged (BM=128),
//      8=bf16 LDS-staged, 9=bf16 gelu LDS-staged, 10=f32 LDS-staged (any BM).
template<int BM, int BN, int WR, int WC, int EPI, int PIPE = 0>
__device__ __forceinline__ void gemm_dev(
    short* __restrict__ lds,
    const __hip_bfloat16* __restrict__ A, int lda, long sA,
    const __hip_bfloat16* __restrict__ Bt, int ldb, long sB,
    const float* __restrict__ bias,
    const float* __restrict__ aux,
    void* __restrict__ Cv, int ldc, long sC,
    int Kdim, int bm, int bn, int z)
{
    constexpr int FM = BM / WR / 16;
    constexpr int FN = BN / WC / 16;
    constexpr int ACH = BM * 8;
    constexpr int BCH = BN * 8;
    constexpr int HALF = (BM + BN) * 64;
    A  += (long)z * sA;
    Bt += (long)z * sB;
    const int tid = threadIdx.x;
    const int w = tid >> 6, lane = tid & 63;
    const int wr = w / WC, wc = w % WC;
    const int moff = wr * (BM / WR), noff = wc * (BN / WC);
    floatx4 acc[FM][FN] = {};

    auto stage = [&](int buf, int k0) {
        char* baseA = (char*)(lds + buf * HALF);
        char* baseB = (char*)(lds + buf * HALF + BM * 64);
        #pragma unroll
        for (int i = 0; i < ACH / 256; i++) {
            int c = tid + i * 256;
            int m = c >> 3, u = (c & 7) ^ (m & 7);
            GLOAD16(A + (long)(bm + m) * lda + k0 + u * 8, baseA + (w * 64 + i * 256) * 16);
        }
        #pragma unroll
        for (int i = 0; i < BCH / 256; i++) {
            int c = tid + i * 256;
            int m = c >> 3, u = (c & 7) ^ (m & 7);
            GLOAD16(Bt + (long)(bn + m) * ldb + k0 + u * 8, baseB + (w * 64 + i * 256) * 16);
        }
    };

    auto compute = [&](int buf) {
        const char* baseA = (const char*)(lds + buf * HALF);
        const char* baseB = (const char*)(lds + buf * HALF + BM * 64);
        #pragma unroll
        for (int kk = 0; kk < 2; kk++) {
            bhalf8 af[FM], bf[FN];
            #pragma unroll
            for (int fm = 0; fm < FM; fm++) {
                int row = moff + fm * 16 + (lane & 15);
                int u = (kk * 4 + (lane >> 4)) ^ (row & 7);
                af[fm] = *(const bhalf8*)(baseA + row * 128 + u * 16);
            }
            #pragma unroll
            for (int fn = 0; fn < FN; fn++) {
                int row = noff + fn * 16 + (lane & 15);
                int u = (kk * 4 + (lane >> 4)) ^ (row & 7);
                bf[fn] = *(const bhalf8*)(baseB + row * 128 + u * 16);
            }
            #pragma unroll
            for (int fm = 0; fm < FM; fm++)
                #pragma unroll
                for (int fn = 0; fn < FN; fn++)
                    acc[fm][fn] = __builtin_amdgcn_mfma_f32_16x16x32_bf16(
                        af[fm], bf[fn], acc[fm][fn], 0, 0, 0);
        }
    };

    const int nt = Kdim >> 6;
    if constexpr (PIPE == 0) {
        stage(0, 0);
        __syncthreads();
        int cur = 0;
        for (int t = 0; t < nt; ++t) {
            if (t + 1 < nt) stage(cur ^ 1, (t + 1) * 64);
            compute(cur);
            __syncthreads();
            cur ^= 1;
        }
    } else {
        // 3-buffer, 2 stages in flight; one stage (4 loads) crosses barriers.
        stage(0, 0);
        stage(1, 64);
        __syncthreads();              // full drain once (stage 0+1 landed)
        for (int t = 0; t < nt; ++t) {
            if (t + 2 < nt) stage((t + 2) % 3, (t + 2) * 64);
            compute(t % 3);
            if (t + 2 < nt) {
                asm volatile("s_waitcnt vmcnt(4)" ::: "memory");
            } else {
                asm volatile("s_waitcnt vmcnt(0)" ::: "memory");
            }
            __builtin_amdgcn_s_barrier();
        }
    }

    float* Cf = (float*)Cv;
    __hip_bfloat16* Cb = (__hip_bfloat16*)Cv;
    __hip_bfloat16* vtb = (EPI == 5) ? (__hip_bfloat16*)(void*)aux : nullptr;
    const long zoff = (long)z * sC;
    const int lr = lane >> 4, lc = lane & 15;

    if constexpr (EPI == 7) {
        // two-half staged f32 coalesced store (needs WR=2, FM=4)
        float* st = (float*)lds;
        constexpr int STR = BN + 4;
        #pragma unroll
        for (int h = 0; h < 2; h++) {
            __syncthreads();
            #pragma unroll
            for (int fm = 0; fm < FM; fm++) {
                int rowbase = moff + fm * 16;
                if (((rowbase >> 5) & 1) != h) continue;
                int crow0 = (rowbase & 31) + ((rowbase >> 6) << 5);
                #pragma unroll
                for (int fn = 0; fn < FN; fn++) {
                    int col = noff + fn * 16 + lc;
                    #pragma unroll
                    for (int i = 0; i < 4; i++)
                        st[(crow0 + lr * 4 + i) * STR + col] = acc[fm][fn][i];
                }
            }
            __syncthreads();
            constexpr int ITERS = (BM / 2) * BN / 4 / 256;
            #pragma unroll
            for (int it = 0; it < ITERS; it++) {
                int slot = it * 256 + tid;
                int crow = slot / (BN / 4), c4 = (slot % (BN / 4)) * 4;
                int r = (crow & 31) + ((crow >> 5) << 6) + h * 32;
                *(float4*)&Cf[zoff + (long)(bm + r) * ldc + bn + c4] =
                    *(float4*)&st[crow * STR + c4];
            }
        }
        return;
    }
    if constexpr (EPI == 10) {
        // f32 staged coalesced store, any BM (needs BM*(BN+4)*4 bytes in arena)
        float* st = (float*)lds;
        constexpr int STR = BN + 4;
        __syncthreads();
        #pragma unroll
        for (int fm = 0; fm < FM; fm++)
            #pragma unroll
            for (int fn = 0; fn < FN; fn++)
                #pragma unroll
                for (int i = 0; i < 4; i++)
                    st[(moff + fm * 16 + lr * 4 + i) * STR + noff + fn * 16 + lc] =
                        acc[fm][fn][i];
        __syncthreads();
        constexpr int ITERS = BM * BN / 4 / 256;
        #pragma unroll
        for (int it = 0; it < ITERS; it++) {
            int slot = it * 256 + tid;
            int r = slot / (BN / 4), c4 = (slot % (BN / 4)) * 4;
            *(float4*)&Cf[zoff + (long)(bm + r) * ldc + bn + c4] =
                *(float4*)&st[r * STR + c4];
        }
        return;
    }
    if constexpr (EPI == 8 || EPI == 9) {
        short* sh = lds;
        constexpr int STR = BN + 8;
        __syncthreads();
        #pragma unroll
        for (int fm = 0; fm < FM; fm++) {
            #pragma unroll
            for (int fn = 0; fn < FN; fn++) {
                int col = noff + fn * 16 + lc;
                float bv = bias ? bias[bn + col] : 0.f;
                #pragma unroll
                for (int i = 0; i < 4; i++) {
                    float v = acc[fm][fn][i] + bv;
                    if (EPI == 9) v = gelu_f(v);
                    sh[(moff + fm * 16 + lr * 4 + i) * STR + col] =
                        __bfloat16_as_short(__float2bfloat16(v));
                }
            }
        }
        __syncthreads();
        constexpr int ITERS = BM * BN / 8 / 256;
        #pragma unroll
        for (int it = 0; it < ITERS; it++) {
            int slot = it * 256 + tid;
            int r = slot / (BN / 8), c8 = (slot % (BN / 8)) * 8;
            *(uint4*)&Cb[zoff + (long)(bm + r) * ldc + bn + c8] =
                *(uint4*)&sh[r * STR + c8];
        }
        return;
    }

    float alphaV = (EPI == 3) ? bias[0] : 0.f;
    #pragma unroll
    for (int fm = 0; fm < FM; fm++) {
        #pragma unroll
        for (int fn = 0; fn < FN; fn++) {
            int cN = bn + noff + fn * 16 + lc;
            float bv = (EPI == 3 || !bias || (EPI == 6 && z != 0)) ? 0.f : bias[cN];
            #pragma unroll
            for (int i = 0; i < 4; i++) {
                int rM = bm + moff + fm * 16 + lr * 4 + i;
                long idx = zoff + (long)rM * ldc + cN;
                float v = acc[fm][fn][i] + bv;
                if constexpr (EPI == 0) Cf[idx] = v;
                else if constexpr (EPI == 1) Cb[idx] = __float2bfloat16(v);
                else if constexpr (EPI == 2) Cb[idx] = __float2bfloat16(gelu_f(v));
                else if constexpr (EPI == 3)
                    Cb[idx] = __float2bfloat16(aux[idx] + alphaV * acc[fm][fn][i]);
                else if constexpr (EPI == 4) Cf[idx] += v;
                else if constexpr (EPI == 5) {
                    __hip_bfloat16 bvv = __float2bfloat16(v);
                    Cb[idx] = bvv;
                    if (cN >= 1024) {
                        int hh = (cN - 1024) >> 6, dh = (cN - 1024) & 63;
                        int bb = rM >> 9, ss = rM & 511;
                        vtb[(((long)bb * 8 + hh) * 64 + dh) * 512 + ss] = bvv;
                    }
                }
                else if constexpr (EPI == 6) atomicAdd(&Cf[idx], v);
            }
        }
    }
}

// standalone GEMM wrapper. SWZ=1: XCD-bijective head mapping.
template<int BM, int BN, int WR, int WC, int EPI, int SWZ = 0, int PIPE = 0>
__global__ __launch_bounds__(256) void gemm_mfma(
    const __hip_bfloat16* __restrict__ A, int lda, long sA,
    const __hip_bfloat16* __restrict__ Bt, int ldb, long sB,
    const float* __restrict__ bias,
    const float* __restrict__ aux,
    void* __restrict__ Cv, int ldc, long sC,
    int Kdim)
{
    __shared__ short lds[(PIPE ? 3 : 2) * (BM + BN) * 64];
    int bm, bn;
    if constexpr (SWZ == 1) {
        constexpr int MT = T_ / BM;
        constexpr int NP = V_ / BN;
        constexpr int PPX = (NP + 7) / 8;
        int d = blockIdx.x;
        int xcd = d & 7, k = d >> 3;
        int ty = xcd * PPX + k / MT;
        if (ty >= NP) return;
        bm = (k % MT) * BM;
        bn = ty * BN;
    } else {
        bm = blockIdx.y * BM;
        bn = blockIdx.x * BN;
    }
    gemm_dev<BM, BN, WR, WC, EPI, PIPE>(lds, A, lda, sA, Bt, ldb, sB, bias, aux,
                                        Cv, ldc, sC, Kdim, bm, bn, blockIdx.z);
}

// ---------------------------------------------- mega dispatch: QKV + Wsne + proj
// blocks [0,384): QKV 64x64 PIPE1; [384,400): WsneK PIPE1; [400,912): proj 64x64 PIPE1.
__global__ __launch_bounds__(256) void mega_gemm(
    const __hip_bfloat16* __restrict__ catB, const __hip_bfloat16* __restrict__ qkvT,
    const float* __restrict__ bqkv, __hip_bfloat16* __restrict__ VtB,
    __hip_bfloat16* __restrict__ qkvB,
    const __hip_bfloat16* __restrict__ WsB, const __hip_bfloat16* __restrict__ neB,
    __hip_bfloat16* __restrict__ WsneK,
    const __hip_bfloat16* __restrict__ n2B, const __hip_bfloat16* __restrict__ projT,
    __hip_bfloat16* __restrict__ Pb)
{
    __shared__ short lds[24576];   // 48 KB: 3x(64+64)x64
    int blk = blockIdx.x;
    if (blk < 384) {
        gemm_dev<64, 64, 2, 2, 5, 1>(lds, catB, 1024, 0, qkvT, D_, 0, bqkv,
                                     (const float*)VtB, qkvB, 1536, 0, D_,
                                     (blk / 24) * 64, (blk % 24) * 64, 0);
    } else if (blk < 400) {
        gemm_dev<64, 64, 2, 2, 1, 1>(lds, WsB, D_, 0, neB, D_, 0, nullptr, nullptr,
                                     WsneK, N_, 0, D_, (blk - 384) * 64, 0, 0);
    } else {
        int local = blk - 400;
        gemm_dev<64, 64, 2, 2, 8, 1>(lds, n2B, D_, 0, projT, D_, (long)R_ * D_,
                                     nullptr, nullptr, Pb, NB_ * R_, R_, D_,
                                     (local & 15) * 64, 0, local >> 4);
    }
}

// ------------------------------------------------------------- flash attention
__global__ __launch_bounds__(256) void attn_mfma(
    const __hip_bfloat16* __restrict__ qkv,
    const __hip_bfloat16* __restrict__ vt,
    __hip_bfloat16* __restrict__ catB)
{
    __shared__ short pbuf[4][16][72];
    const int tid = threadIdx.x;
    const int w = tid >> 6, lane = tid & 63;
    const int g = lane >> 4, ql = lane & 15;
    const int h = blockIdx.y, b = blockIdx.z;
    const int qbase = blockIdx.x * 64 + w * 16;

    const long qrow = ((long)(b * S_ + qbase + ql)) * 1536 + h * DH_;
    bhalf8 qa0 = *(const bhalf8*)(qkv + qrow + g * 8);
    bhalf8 qa1 = *(const bhalf8*)(qkv + qrow + 32 + g * 8);
    const __hip_bfloat16* kB = qkv + 512;
    const __hip_bfloat16* vbase = vt + ((long)(b * H_ + h)) * DH_ * S_;

    floatx4 o[4] = {};
    float m = -INFINITY, ls = 0.f;
    const float SC = 0.125f * 1.44269504088896f;
    const int nblk = blockIdx.x + 1;

    for (int kvb = 0; kvb < nblk; kvb++) {
        const int kb0 = kvb * 64;
        floatx4 st[4];
        #pragma unroll
        for (int t = 0; t < 4; t++) {
            long krow = ((long)(b * S_ + kb0 + t * 16 + ql)) * 1536 + h * DH_;
            bhalf8 ka0 = *(const bhalf8*)(kB + krow + g * 8);
            bhalf8 ka1 = *(const bhalf8*)(kB + krow + 32 + g * 8);
            floatx4 z = {};
            z = __builtin_amdgcn_mfma_f32_16x16x32_bf16(ka0, qa0, z, 0, 0, 0);
            z = __builtin_amdgcn_mfma_f32_16x16x32_bf16(ka1, qa1, z, 0, 0, 0);
            st[t] = z;
        }
        const int q = qbase + ql;
        float p[4][4];
        float m4 = -INFINITY;
        #pragma unroll
        for (int t = 0; t < 4; t++)
            #pragma unroll
            for (int i = 0; i < 4; i++) {
                int kv = kb0 + t * 16 + g * 4 + i;
                float v = (kv <= q) ? st[t][i] * SC : -INFINITY;
                p[t][i] = v; m4 = fmaxf(m4, v);
            }
        m4 = fmaxf(m4, __shfl_xor(m4, 16));
        m4 = fmaxf(m4, __shfl_xor(m4, 32));
        float mnew = fmaxf(m, m4);
        float corr = exp2f(m - mnew);
        m = mnew;
        float lsum = 0.f;
        #pragma unroll
        for (int t = 0; t < 4; t++)
            #pragma unroll
            for (int i = 0; i < 4; i++) {
                float e = exp2f(p[t][i] - mnew);
                p[t][i] = e; lsum += e;
            }
        lsum += __shfl_xor(lsum, 16);
        lsum += __shfl_xor(lsum, 32);
        ls = ls * corr + lsum;
        unsigned* prow = (unsigned*)&pbuf[w][ql][0];
        #pragma unroll
        for (int t = 0; t < 4; t++) {
            prow[t * 8 + g * 2]     = pk2(p[t][0], p[t][1]);
            prow[t * 8 + g * 2 + 1] = pk2(p[t][2], p[t][3]);
        }
        #pragma unroll
        for (int i = 0; i < 4; i++) {
            float c = __shfl(corr, g * 4 + i);
            #pragma unroll
            for (int dt = 0; dt < 4; dt++) o[dt][i] *= c;
        }
        __syncthreads();
        #pragma unroll
        for (int ks = 0; ks < 2; ks++) {
            bhalf8 pa = *(const bhalf8*)&pbuf[w][ql][ks * 32 + g * 8];
            #pragma unroll
            for (int dt = 0; dt < 4; dt++) {
                bhalf8 vb = *(const bhalf8*)(vbase + (long)(dt * 16 + ql) * S_ + kb0 + ks * 32 + g * 8);
                o[dt] = __builtin_amdgcn_mfma_f32_16x16x32_bf16(pa, vb, o[dt], 0, 0, 0);
            }
        }
        __syncthreads();
    }
    const float inv = 1.f / ls;
    #pragma unroll
    for (int i = 0; i < 4; i++) {
        float iv = __shfl(inv, g * 4 + i);
        int trow = b * S_ + qbase + g * 4 + i;
        #pragma unroll
        for (int dt = 0; dt < 4; dt++)
            catB[(long)trow * 1024 + 512 + h * DH_ + dt * 16 + ql] =
                __float2bfloat16(o[dt][i] * iv);
    }
}

// ------------------------------------------------------------- merged prologue
__device__ __forceinline__ void tcvt_dev(const float* in, int ldn, long sIn,
                                         __hip_bfloat16* out, int ldk, long sOut,
                                         int bx, int by, int bz, float (*tsh)[33]) {
    in  += (long)bz * sIn;
    out += (long)bz * sOut;
    int k0 = by * 32, n0 = bx * 32;
    int tx = threadIdx.x & 31, ty = threadIdx.x >> 5;
    #pragma unroll
    for (int r = 0; r < 4; r++) tsh[ty * 4 + r][tx] = in[(long)(k0 + ty * 4 + r) * ldn + n0 + tx];
    __syncthreads();
    #pragma unroll
    for (int r = 0; r < 4; r++)
        out[(long)(n0 + ty * 4 + r) * ldk + k0 + tx] = __float2bfloat16(tsh[tx][ty * 4 + r]);
}

__device__ __forceinline__ void cvt8(const float* in, __hip_bfloat16* out, long i) {
    float4 v0 = *(const float4*)(in + i);
    float4 v1 = *(const float4*)(in + i + 4);
    uint4 pkv = make_uint4(pk2(v0.x, v0.y), pk2(v0.z, v0.w),
                           pk2(v1.x, v1.y), pk2(v1.z, v1.w));
    *(uint4*)(out + i) = pkv;
}

__global__ __launch_bounds__(256) void prologue_kernel(
    const float* __restrict__ temb, __hip_bfloat16* __restrict__ tembB,
    const float* __restrict__ basisA, __hip_bfloat16* __restrict__ projT,
    __hip_bfloat16* __restrict__ deltaT,
    const float* __restrict__ bq, const float* __restrict__ bk,
    const float* __restrict__ bv, float* __restrict__ bqkv,
    const float* __restrict__ Wq, const float* __restrict__ Wk,
    const float* __restrict__ Wv, __hip_bfloat16* __restrict__ qkvT,
    const float* __restrict__ Wup, __hip_bfloat16* __restrict__ WupT,
    const float* __restrict__ Wdn, __hip_bfloat16* __restrict__ WdnT,
    const float* __restrict__ Ws, __hip_bfloat16* __restrict__ WsB,
    const int* __restrict__ ids, const float* __restrict__ pemb,
    float* __restrict__ x)
{
    __shared__ float tsh[32][33];
    const int blk = blockIdx.x, tid = threadIdx.x;
    if (blk < 8000) {
        cvt8(temb, tembB, ((long)blk * 256 + tid) * 8);
    } else if (blk < 12096) {
        long i = (long)(blk - 8000) * 256 + tid;
        int r = i & 63; int d = (i >> 6) & 511; int n = i >> 15;
        __hip_bfloat16 v = __float2bfloat16(basisA[i]);
        projT[((long)n * R_ + r) * D_ + d] = v;
        deltaT[(long)d * (NB_ * R_) + n * R_ + r] = v;
    } else if (blk < 12120) {
        int i = (blk - 12096) * 256 + tid;
        int l = i / 1536, j = i % 1536;
        float v = (j < 512) ? bq[l * 512 + j] : (j < 1024) ? bk[l * 512 + j - 512]
                                                           : bv[l * 512 + j - 1024];
        bqkv[i] = v;
    } else if (blk < 13144) {
        int lin = blk - 12120;
        tcvt_dev(Wq, D_, (long)D_ * D_, qkvT, D_, (long)1536 * D_,
                 lin & 15, (lin >> 4) & 15, lin >> 8, tsh);
    } else if (blk < 14168) {
        int lin = blk - 13144;
        tcvt_dev(Wk, D_, (long)D_ * D_, qkvT + 512 * 512, D_, (long)1536 * D_,
                 lin & 15, (lin >> 4) & 15, lin >> 8, tsh);
    } else if (blk < 15192) {
        int lin = blk - 14168;
        tcvt_dev(Wv, D_, (long)D_ * D_, qkvT + 1024 * 512, D_, (long)1536 * D_,
                 lin & 15, (lin >> 4) & 15, lin >> 8, tsh);
    } else if (blk < 19288) {
        int lin = blk - 15192;
        tcvt_dev(Wup, DFF_, (long)D_ * DFF_, WupT, D_, (long)D_ * DFF_,
                 lin & 63, (lin >> 6) & 15, lin >> 10, tsh);
    } else if (blk < 23384) {
        int lin = blk - 19288;
        tcvt_dev(Wdn, D_, (long)DFF_ * D_, WdnT, DFF_, (long)DFF_ * D_,
                 lin & 15, (lin >> 4) & 63, lin >> 10, tsh);
    } else if (blk < 24408) {
        cvt8(Ws, WsB, ((long)(blk - 23384) * 256 + tid) * 8);
    } else {
        int t = blk - 24408;
        int s = t % S_;
        int id = ids[t];
        for (int d = tid; d < D_; d += 256)
            x[(long)t * D_ + d] = temb[(long)id * D_ + d] + pemb[(long)s * D_ + d];
    }
}

// ------------------------------------------------------------- wave-per-row LN
__device__ __forceinline__ float wave_sum(float v) {
    #pragma unroll
    for (int off = 1; off < 64; off <<= 1) v += __shfl_xor(v, off);
    return v;
}

__device__ __forceinline__ void ln_wave(const float* __restrict__ row,
                                        const float* __restrict__ g,
                                        const float* __restrict__ b,
                                        float* __restrict__ outf,
                                        __hip_bfloat16* __restrict__ outb,
                                        int ldo, long t) {
    int lane = threadIdx.x & 63;
    float4 a0 = *(const float4*)(row + lane * 8);
    float4 a1 = *(const float4*)(row + lane * 8 + 4);
    float v[8] = {a0.x, a0.y, a0.z, a0.w, a1.x, a1.y, a1.z, a1.w};
    float s = 0.f;
    #pragma unroll
    for (int j = 0; j < 8; j++) s += v[j];
    float mean = wave_sum(s) * (1.0f / D_);
    float vs = 0.f;
    #pragma unroll
    for (int j = 0; j < 8; j++) { v[j] -= mean; vs += v[j] * v[j]; }
    float rstd = rsqrtf(wave_sum(vs) * (1.0f / D_) + 1e-5f);
    float4 g0 = *(const float4*)(g + lane * 8), g1 = *(const float4*)(g + lane * 8 + 4);
    float4 b0 = *(const float4*)(b + lane * 8), b1 = *(const float4*)(b + lane * 8 + 4);
    float gg[8] = {g0.x, g0.y, g0.z, g0.w, g1.x, g1.y, g1.z, g1.w};
    float bb[8] = {b0.x, b0.y, b0.z, b0.w, b1.x, b1.y, b1.z, b1.w};
    float o[8];
    #pragma unroll
    for (int j = 0; j < 8; j++) o[j] = v[j] * rstd * gg[j] + bb[j];
    if (outf) {
        *(float4*)(outf + t * D_ + lane * 8)     = make_float4(o[0], o[1], o[2], o[3]);
        *(float4*)(outf + t * D_ + lane * 8 + 4) = make_float4(o[4], o[5], o[6], o[7]);
    }
    uint4 pkv = make_uint4(pk2(o[0], o[1]), pk2(o[2], o[3]), pk2(o[4], o[5]), pk2(o[6], o[7]));
    *(uint4*)(outb + (long)t * ldo + lane * 8) = pkv;
}

// blocks 0-255: ln1 (4 rows) -> catB; 256-511: ln2 -> buf1+n2B; 512-575: ne
__global__ __launch_bounds__(256) void prep_kernel(
    const float* __restrict__ x,
    const float* __restrict__ ln1g, const float* __restrict__ ln1b,
    const float* __restrict__ ln2g, const float* __restrict__ ln2b,
    const float* __restrict__ rec, const float* __restrict__ bemb,
    const float* __restrict__ bs,
    __hip_bfloat16* __restrict__ catB, float* __restrict__ buf1,
    __hip_bfloat16* __restrict__ n2B,
    __hip_bfloat16* __restrict__ neb, float* __restrict__ sel,
    float* __restrict__ bsne)
{
    int blk = blockIdx.x, tid = threadIdx.x, w = tid >> 6;
    if (blk < 256) {
        long t = blk * 4 + w;
        ln_wave(x + t * D_, ln1g, ln1b, nullptr, catB, 1024, t);
    } else if (blk < 512) {
        long t = (blk - 256) * 4 + w;
        ln_wave(x + t * D_, ln2g, ln2b, buf1, n2B, 512, t);
    } else {
        __shared__ float red[256];
        __shared__ float wsm[NB_];
        int n = blk - 512;
        if (tid == 0) {
            float mx = -1e30f;
            for (int i = 0; i < NB_; i++) mx = fmaxf(mx, rec[n * NB_ + i]);
            float sm = 0.f;
            for (int i = 0; i < NB_; i++) { float e = expf(rec[n * NB_ + i] - mx); wsm[i] = e; sm += e; }
            float inv = 1.f / sm;
            for (int i = 0; i < NB_; i++) wsm[i] *= inv;
        }
        __syncthreads();
        if (tid < NB_) sel[n * NB_ + tid] = wsm[tid];
        float part = 0.f;
        for (int d = tid; d < D_; d += 256) {
            float acc = 0.f;
            #pragma unroll
            for (int nb = 0; nb < NB_; nb++) acc += wsm[nb] * bemb[nb * D_ + d];
            neb[(long)n * D_ + d] = __float2bfloat16(acc);
            part += bs[d] * acc;
        }
        red[tid] = part; __syncthreads();
        for (int off = 128; off; off >>= 1) { if (tid < off) red[tid] += red[tid + off]; __syncthreads(); }
        if (tid == 0) bsne[n] = red[0];
    }
}

// ------------------------------------------------------------- final LN (4 rows/block)
__global__ __launch_bounds__(256) void ln_kernel(const float* __restrict__ in,
                                                 const float* __restrict__ g,
                                                 const float* __restrict__ b,
                                                 __hip_bfloat16* __restrict__ outb) {
    long t = blockIdx.x * 4 + (threadIdx.x >> 6);
    ln_wave(in + t * D_, g, b, nullptr, outb, 512, t);
}

// ------------------------------- scores + route + hg (one block per token)
__global__ __launch_bounds__(256) void route_hg(
    const __hip_bfloat16* __restrict__ catB, const __hip_bfloat16* __restrict__ WsneK,
    const float* __restrict__ bsne, const float* __restrict__ sel,
    const __hip_bfloat16* __restrict__ Pb, __hip_bfloat16* __restrict__ g)
{
    int t = blockIdx.x, tid = threadIdx.x;
    __shared__ float catf[1024];
    __shared__ float part[4][64];
    __shared__ float trl[32];
    __shared__ float hl[64];
    {
        short4 vv = *(const short4*)(catB + (long)t * 1024 + tid * 4);
        catf[tid * 4 + 0] = __bfloat162float(*(__hip_bfloat16*)&vv.x);
        catf[tid * 4 + 1] = __bfloat162float(*(__hip_bfloat16*)&vv.y);
        catf[tid * 4 + 2] = __bfloat162float(*(__hip_bfloat16*)&vv.z);
        catf[tid * 4 + 3] = __bfloat162float(*(__hip_bfloat16*)&vv.w);
    }
    __syncthreads();
    int n = tid & 63, q = tid >> 6;
    {
        const __hip_bfloat16* wp = WsneK + (long)q * 256 * 64 + n;
        const float* cf = catf + q * 256;
        float a0 = 0.f, a1 = 0.f, a2 = 0.f, a3 = 0.f;
        #pragma unroll 16
        for (int j = 0; j < 256; j += 4) {
            a0 = fmaf(cf[j],     __bfloat162float(wp[(j)     * 64]), a0);
            a1 = fmaf(cf[j + 1], __bfloat162float(wp[(j + 1) * 64]), a1);
            a2 = fmaf(cf[j + 2], __bfloat162float(wp[(j + 2) * 64]), a2);
            a3 = fmaf(cf[j + 3], __bfloat162float(wp[(j + 3) * 64]), a3);
        }
        part[q][n] = (a0 + a1) + (a2 + a3);
    }
    __syncthreads();
    if (tid < 64) {
        int lane = tid;
        float myval = part[0][lane] + part[1][lane] + part[2][lane] + part[3][lane] + bsne[lane];
        float topv[K_]; int topi[K_];
        #pragma unroll
        for (int kk = 0; kk < K_; kk++) {
            float v = myval; int idx = lane;
            #pragma unroll
            for (int off = 32; off; off >>= 1) {
                float ov = __shfl_down(v, off);
                int oi = __shfl_down(idx, off);
                if (ov > v || (ov == v && oi < idx)) { v = ov; idx = oi; }
            }
            v = __shfl(v, 0); idx = __shfl(idx, 0);
            topv[kk] = v; topi[kk] = idx;
            if (lane == idx) myval = -INFINITY;
        }
        float mx = topv[0];
        float wgt[K_], sum = 0.f;
        #pragma unroll
        for (int kk = 0; kk < K_; kk++) { wgt[kk] = expf(topv[kk] - mx); sum += wgt[kk]; }
        float inv = 1.f / sum;
        if (lane < NB_) {
            float a = 0.f;
            #pragma unroll
            for (int kk = 0; kk < K_; kk++) a += wgt[kk] * inv * sel[topi[kk] * NB_ + lane];
            trl[lane] = a;
        }
    }
    __syncthreads();
    if (tid < 64) {
        float acc = 0.f;
        const __hip_bfloat16* p = Pb + (long)t * 2048 + tid;
        #pragma unroll
        for (int nn = 0; nn < 32; nn++) acc += trl[nn] * __bfloat162float(p[nn * 64]);
        hl[tid] = acc;
    }
    __syncthreads();
    #pragma unroll
    for (int j = 0; j < 8; j++) {
        int idx = tid * 8 + j;
        int nn = idx >> 6, r = idx & 63;
        g[(long)t * 2048 + idx] = __float2bfloat16(trl[nn] * hl[r]);
    }
}

// ------------------------------------------------------------- launch
extern "C" void kernel_launch(void* const* d_in, const int* in_sizes, int n_in,
                              void* d_out, int out_size, void* d_ws, size_t ws_size,
                              hipStream_t stream) {
    const int*   ids    = (const int*)d_in[0];
    const float* temb   = (const float*)d_in[1];
    const float* pemb   = (const float*)d_in[2];
    const float* basisA = (const float*)d_in[3];
    const float* bemb   = (const float*)d_in[4];
    const float* recipe = (const float*)d_in[5];
    const float* Wq = (const float*)d_in[6],  *bq = (const float*)d_in[7];
    const float* Wk = (const float*)d_in[8],  *bk = (const float*)d_in[9];
    const float* Wv = (const float*)d_in[10], *bv = (const float*)d_in[11];
    const float* Ws = (const float*)d_in[12], *bs = (const float*)d_in[13];
    const float* Wup = (const float*)d_in[14], *bup = (const float*)d_in[15];
    const float* Wdn = (const float*)d_in[16], *bdn = (const float*)d_in[17];
    const float* ln1g = (const float*)d_in[18], *ln1b = (const float*)d_in[19];
    const float* ln2g = (const float*)d_in[20], *ln2b = (const float*)d_in[21];
    const float* alpha = (const float*)d_in[22];
    const float* lnfg = (const float*)d_in[23], *lnfb = (const float*)d_in[24];
    float* out = (float*)d_out;
    float* W = (float*)d_ws;

    // fp32 arena (float offsets)
    float* x    = W + 0;          // 524288
    float* buf1 = W + 524288;     // n2 f32 (xf input)
    float* bsne = W + 1114112;    // 64
    float* sel  = W + 1212416;    // 2048
    float* bqkv = W + 3835904;    // 6144
    // bf16 arena
    __hip_bfloat16* SB = (__hip_bfloat16*)(W + 3844096);
    __hip_bfloat16* tembB  = SB + 0;          // 16384000
    __hip_bfloat16* qkvT   = SB + 16384000;   // 3145728
    __hip_bfloat16* WsB    = SB + 19529728;   // 2097152
    __hip_bfloat16* WupT   = SB + 21626880;   // 4194304
    __hip_bfloat16* WdnT   = SB + 25821184;   // 4194304
    __hip_bfloat16* projT  = SB + 30015488;   // 1048576
    __hip_bfloat16* deltaT = SB + 31064064;   // 1048576
    __hip_bfloat16* neB    = SB + 32112640;   // 32768
    __hip_bfloat16* catB   = SB + 32145408;   // 1048576
    __hip_bfloat16* WsneK  = SB + 33193984;   // 65536 ([1024][64])
    __hip_bfloat16* n2B    = SB + 33718272;   // 524288
    __hip_bfloat16* xfB    = SB + 34242560;   // 524288
    __hip_bfloat16* gB     = SB + 34766848;   // 2097152
    __hip_bfloat16* ffhB   = SB + 36864000;   // 2097152
    __hip_bfloat16* qkvB   = SB + 38961152;   // 1572864
    __hip_bfloat16* VtB    = SB + 40534016;   // 524288
    __hip_bfloat16* Pb     = SB + 41058304;   // 2097152 ([1024][2048])

    dim3 blk(256);
    prologue_kernel<<<25432, blk, 0, stream>>>(
        temb, tembB, basisA, projT, deltaT, bq, bk, bv, bqkv,
        Wq, Wk, Wv, qkvT, Wup, WupT, Wdn, WdnT, Ws, WsB, ids, pemb, x);

    for (int l = 0; l < L_; l++) {
        prep_kernel<<<576, blk, 0, stream>>>(
            x, ln1g + l * D_, ln1b + l * D_, ln2g + l * D_, ln2b + l * D_,
            recipe + (long)l * N_ * NB_, bemb, bs + l * D_,
            catB, buf1, n2B, neB, sel, bsne);
        // QKV + Wsne + proj, all 64x64 PIPE1, one dispatch
        mega_gemm<<<912, blk, 0, stream>>>(
            catB, qkvT + (long)l * 1536 * 512, bqkv + l * 1536, VtB, qkvB,
            WsB + (long)l * 1024 * 512, neB, WsneK, n2B, projT, Pb);
        attn_mfma<<<dim3(8, H_, B_), blk, 0, stream>>>(qkvB, VtB, catB);
        // scores + top-k route + h/g (merged)
        route_hg<<<T_, blk, 0, stream>>>(catB, WsneK, bsne, sel, Pb, gB);
        // delta GEMM + fused xf (3-buf pipeline)
        gemm_mfma<64, 64, 2, 2, 3, 0, 1><<<dim3(8, 16), blk, 0, stream>>>(
            gB, NB_ * R_, 0, deltaT, NB_ * R_, 0, alpha + l, buf1,
            xfB, D_, 0, NB_ * R_);
        // FFN up (+gelu, 3-buf pipeline)
        gemm_mfma<64, 64, 2, 2, 2, 0, 1><<<dim3(32, 16), blk, 0, stream>>>(
            xfB, D_, 0, WupT + (long)l * D_ * DFF_, D_, 0, bup + l * DFF_, nullptr,
            ffhB, DFF_, 0, D_);
        // FFN down, split-K=2, fused residual (atomic, 3-buf pipeline)
        gemm_mfma<64, 64, 2, 2, 6, 0, 1><<<dim3(8, 16, 2), blk, 0, stream>>>(
            ffhB, DFF_, 1024, WdnT + (long)l * DFF_ * D_, DFF_, 1024, bdn + l * D_, nullptr,
            x, D_, 0, 1024);
    }
    // final LN + tied head (64x64 PIPE1, XCD-bijective, staged f32 stores)
    ln_kernel<<<256, blk, 0, stream>>>(x, lnfg, lnfb, n2B);
    gemm_mfma<64, 64, 2, 2, 10, 1, 1><<<dim3(8064), blk, 0, stream>>>(
        n2B, D_, 0, tembB, D_, 0, nullptr, nullptr, out, V_, 0, D_);
}

// Round 16
// 500.522 us; speedup vs baseline: 1.0160x; 1.0160x over previous
//
#include <hip/hip_runtime.h>
#include <hip/hip_bf16.h>
#include <math.h>

// Problem constants
#define V_  32000
#define D_  512
#define DFF_ 2048
#define L_  4
#define H_  8
#define N_  64
#define K_  8
#define NB_ 32
#define R_  64
#define B_  2
#define S_  512
#define T_  1024   // B*S
#define DH_ 64

typedef short bhalf8 __attribute__((ext_vector_type(8)));
typedef float floatx4 __attribute__((ext_vector_type(4)));

#define GLOAD16(gp, lp) __builtin_amdgcn_global_load_lds( \
    (const __attribute__((address_space(1))) void*)(gp), \
    (__attribute__((address_space(3))) void*)(lp), 16, 0, 0)

__device__ __forceinline__ float gelu_f(float v) {
    return 0.5f * v * (1.0f + erff(v * 0.70710678118654752f));
}

__device__ __forceinline__ unsigned pk2(float a, float b) {
    unsigned ua = (unsigned)__bfloat16_as_ushort(__float2bfloat16(a));
    unsigned ub = (unsigned)__bfloat16_as_ushort(__float2bfloat16(b));
    return ua | (ub << 16);
}

// ------------------------------------------------------------- GEMM core
// C[M,N] = A[M,K] @ Bt[N,K]^T (+bias). bf16, BK=64, XOR-swizzle u^=row&7.
// PIPE=0: classic double-buffer (arena 2*(BM+BN)*64 shorts).
// PIPE=1: 3-buffer counted-vmcnt pipeline (arena 3*(BM+BN)*64 shorts) —
//         one stage (4 loads) stays in flight across each barrier.
// EPI: 0=f32, 1=bf16, 2=bf16 gelu, 3=xf, 4=f32 +=, 5=bf16+Vt scatter,
//      6=f32 atomic, 7=f32 two-half LDS-staged (BM=128),
//      8=bf16 LDS-staged, 9=bf16 gelu LDS-staged, 10=f32 LDS-staged (any BM).
template<int BM, int BN, int WR, int WC, int EPI, int PIPE = 0>
__device__ __forceinline__ void gemm_dev(
    short* __restrict__ lds,
    const __hip_bfloat16* __restrict__ A, int lda, long sA,
    const __hip_bfloat16* __restrict__ Bt, int ldb, long sB,
    const float* __restrict__ bias,
    const float* __restrict__ aux,
    void* __restrict__ Cv, int ldc, long sC,
    int Kdim, int bm, int bn, int z)
{
    constexpr int FM = BM / WR / 16;
    constexpr int FN = BN / WC / 16;
    constexpr int ACH = BM * 8;
    constexpr int BCH = BN * 8;
    constexpr int HALF = (BM + BN) * 64;
    A  += (long)z * sA;
    Bt += (long)z * sB;
    const int tid = threadIdx.x;
    const int w = tid >> 6, lane = tid & 63;
    const int wr = w / WC, wc = w % WC;
    const int moff = wr * (BM / WR), noff = wc * (BN / WC);
    floatx4 acc[FM][FN] = {};

    auto stage = [&](int buf, int k0) {
        char* baseA = (char*)(lds + buf * HALF);
        char* baseB = (char*)(lds + buf * HALF + BM * 64);
        #pragma unroll
        for (int i = 0; i < ACH / 256; i++) {
            int c = tid + i * 256;
            int m = c >> 3, u = (c & 7) ^ (m & 7);
            GLOAD16(A + (long)(bm + m) * lda + k0 + u * 8, baseA + (w * 64 + i * 256) * 16);
        }
        #pragma unroll
        for (int i = 0; i < BCH / 256; i++) {
            int c = tid + i * 256;
            int m = c >> 3, u = (c & 7) ^ (m & 7);
            GLOAD16(Bt + (long)(bn + m) * ldb + k0 + u * 8, baseB + (w * 64 + i * 256) * 16);
        }
    };

    auto compute = [&](int buf) {
        const char* baseA = (const char*)(lds + buf * HALF);
        const char* baseB = (const char*)(lds + buf * HALF + BM * 64);
        #pragma unroll
        for (int kk = 0; kk < 2; kk++) {
            bhalf8 af[FM], bf[FN];
            #pragma unroll
            for (int fm = 0; fm < FM; fm++) {
                int row = moff + fm * 16 + (lane & 15);
                int u = (kk * 4 + (lane >> 4)) ^ (row & 7);
                af[fm] = *(const bhalf8*)(baseA + row * 128 + u * 16);
            }
            #pragma unroll
            for (int fn = 0; fn < FN; fn++) {
                int row = noff + fn * 16 + (lane & 15);
                int u = (kk * 4 + (lane >> 4)) ^ (row & 7);
                bf[fn] = *(const bhalf8*)(baseB + row * 128 + u * 16);
            }
            #pragma unroll
            for (int fm = 0; fm < FM; fm++)
                #pragma unroll
                for (int fn = 0; fn < FN; fn++)
                    acc[fm][fn] = __builtin_amdgcn_mfma_f32_16x16x32_bf16(
                        af[fm], bf[fn], acc[fm][fn], 0, 0, 0);
        }
    };

    const int nt = Kdim >> 6;
    if constexpr (PIPE == 0) {
        stage(0, 0);
        __syncthreads();
        int cur = 0;
        for (int t = 0; t < nt; ++t) {
            if (t + 1 < nt) stage(cur ^ 1, (t + 1) * 64);
            compute(cur);
            __syncthreads();
            cur ^= 1;
        }
    } else {
        // 3-buffer, 2 stages in flight; one stage (4 loads) crosses barriers.
        stage(0, 0);
        stage(1, 64);
        __syncthreads();              // full drain once (stage 0+1 landed)
        for (int t = 0; t < nt; ++t) {
            if (t + 2 < nt) stage((t + 2) % 3, (t + 2) * 64);
            compute(t % 3);
            if (t + 2 < nt) {
                asm volatile("s_waitcnt vmcnt(4)" ::: "memory");
            } else {
                asm volatile("s_waitcnt vmcnt(0)" ::: "memory");
            }
            __builtin_amdgcn_s_barrier();
        }
    }

    float* Cf = (float*)Cv;
    __hip_bfloat16* Cb = (__hip_bfloat16*)Cv;
    __hip_bfloat16* vtb = (EPI == 5) ? (__hip_bfloat16*)(void*)aux : nullptr;
    const long zoff = (long)z * sC;
    const int lr = lane >> 4, lc = lane & 15;

    if constexpr (EPI == 7) {
        // two-half staged f32 coalesced store (needs WR=2, FM=4)
        float* st = (float*)lds;
        constexpr int STR = BN + 4;
        #pragma unroll
        for (int h = 0; h < 2; h++) {
            __syncthreads();
            #pragma unroll
            for (int fm = 0; fm < FM; fm++) {
                int rowbase = moff + fm * 16;
                if (((rowbase >> 5) & 1) != h) continue;
                int crow0 = (rowbase & 31) + ((rowbase >> 6) << 5);
                #pragma unroll
                for (int fn = 0; fn < FN; fn++) {
                    int col = noff + fn * 16 + lc;
                    #pragma unroll
                    for (int i = 0; i < 4; i++)
                        st[(crow0 + lr * 4 + i) * STR + col] = acc[fm][fn][i];
                }
            }
            __syncthreads();
            constexpr int ITERS = (BM / 2) * BN / 4 / 256;
            #pragma unroll
            for (int it = 0; it < ITERS; it++) {
                int slot = it * 256 + tid;
                int crow = slot / (BN / 4), c4 = (slot % (BN / 4)) * 4;
                int r = (crow & 31) + ((crow >> 5) << 6) + h * 32;
                *(float4*)&Cf[zoff + (long)(bm + r) * ldc + bn + c4] =
                    *(float4*)&st[crow * STR + c4];
            }
        }
        return;
    }
    if constexpr (EPI == 10) {
        // f32 staged coalesced store, any BM (needs BM*(BN+4)*4 bytes in arena)
        float* st = (float*)lds;
        constexpr int STR = BN + 4;
        __syncthreads();
        #pragma unroll
        for (int fm = 0; fm < FM; fm++)
            #pragma unroll
            for (int fn = 0; fn < FN; fn++)
                #pragma unroll
                for (int i = 0; i < 4; i++)
                    st[(moff + fm * 16 + lr * 4 + i) * STR + noff + fn * 16 + lc] =
                        acc[fm][fn][i];
        __syncthreads();
        constexpr int ITERS = BM * BN / 4 / 256;
        #pragma unroll
        for (int it = 0; it < ITERS; it++) {
            int slot = it * 256 + tid;
            int r = slot / (BN / 4), c4 = (slot % (BN / 4)) * 4;
            *(float4*)&Cf[zoff + (long)(bm + r) * ldc + bn + c4] =
                *(float4*)&st[r * STR + c4];
        }
        return;
    }
    if constexpr (EPI == 8 || EPI == 9) {
        short* sh = lds;
        constexpr int STR = BN + 8;
        __syncthreads();
        #pragma unroll
        for (int fm = 0; fm < FM; fm++) {
            #pragma unroll
            for (int fn = 0; fn < FN; fn++) {
                int col = noff + fn * 16 + lc;
                float bv = bias ? bias[bn + col] : 0.f;
                #pragma unroll
                for (int i = 0; i < 4; i++) {
                    float v = acc[fm][fn][i] + bv;
                    if (EPI == 9) v = gelu_f(v);
                    sh[(moff + fm * 16 + lr * 4 + i) * STR + col] =
                        __bfloat16_as_short(__float2bfloat16(v));
                }
            }
        }
        __syncthreads();
        constexpr int ITERS = BM * BN / 8 / 256;
        #pragma unroll
        for (int it = 0; it < ITERS; it++) {
            int slot = it * 256 + tid;
            int r = slot / (BN / 8), c8 = (slot % (BN / 8)) * 8;
            *(uint4*)&Cb[zoff + (long)(bm + r) * ldc + bn + c8] =
                *(uint4*)&sh[r * STR + c8];
        }
        return;
    }

    float alphaV = (EPI == 3) ? bias[0] : 0.f;
    #pragma unroll
    for (int fm = 0; fm < FM; fm++) {
        #pragma unroll
        for (int fn = 0; fn < FN; fn++) {
            int cN = bn + noff + fn * 16 + lc;
            float bv = (EPI == 3 || !bias || (EPI == 6 && z != 0)) ? 0.f : bias[cN];
            #pragma unroll
            for (int i = 0; i < 4; i++) {
                int rM = bm + moff + fm * 16 + lr * 4 + i;
                long idx = zoff + (long)rM * ldc + cN;
                float v = acc[fm][fn][i] + bv;
                if constexpr (EPI == 0) Cf[idx] = v;
                else if constexpr (EPI == 1) Cb[idx] = __float2bfloat16(v);
                else if constexpr (EPI == 2) Cb[idx] = __float2bfloat16(gelu_f(v));
                else if constexpr (EPI == 3)
                    Cb[idx] = __float2bfloat16(aux[idx] + alphaV * acc[fm][fn][i]);
                else if constexpr (EPI == 4) Cf[idx] += v;
                else if constexpr (EPI == 5) {
                    __hip_bfloat16 bvv = __float2bfloat16(v);
                    Cb[idx] = bvv;
                    if (cN >= 1024) {
                        int hh = (cN - 1024) >> 6, dh = (cN - 1024) & 63;
                        int bb = rM >> 9, ss = rM & 511;
                        vtb[(((long)bb * 8 + hh) * 64 + dh) * 512 + ss] = bvv;
                    }
                }
                else if constexpr (EPI == 6) atomicAdd(&Cf[idx], v);
            }
        }
    }
}

// standalone GEMM wrapper. SWZ=1: XCD-bijective head mapping.
template<int BM, int BN, int WR, int WC, int EPI, int SWZ = 0, int PIPE = 0>
__global__ __launch_bounds__(256) void gemm_mfma(
    const __hip_bfloat16* __restrict__ A, int lda, long sA,
    const __hip_bfloat16* __restrict__ Bt, int ldb, long sB,
    const float* __restrict__ bias,
    const float* __restrict__ aux,
    void* __restrict__ Cv, int ldc, long sC,
    int Kdim)
{
    __shared__ short lds[(PIPE ? 3 : 2) * (BM + BN) * 64];
    int bm, bn;
    if constexpr (SWZ == 1) {
        constexpr int MT = T_ / BM;
        constexpr int NP = V_ / BN;
        constexpr int PPX = (NP + 7) / 8;
        int d = blockIdx.x;
        int xcd = d & 7, k = d >> 3;
        int ty = xcd * PPX + k / MT;
        if (ty >= NP) return;
        bm = (k % MT) * BM;
        bn = ty * BN;
    } else {
        bm = blockIdx.y * BM;
        bn = blockIdx.x * BN;
    }
    gemm_dev<BM, BN, WR, WC, EPI, PIPE>(lds, A, lda, sA, Bt, ldb, sB, bias, aux,
                                        Cv, ldc, sC, Kdim, bm, bn, blockIdx.z);
}

// ---------------------------------------------- mega dispatch: QKV + Wsne + proj
// blocks [0,384): QKV 64x64 PIPE1; [384,400): WsneK PIPE1; [400,912): proj 64x64 PIPE1.
__global__ __launch_bounds__(256) void mega_gemm(
    const __hip_bfloat16* __restrict__ catB, const __hip_bfloat16* __restrict__ qkvT,
    const float* __restrict__ bqkv, __hip_bfloat16* __restrict__ VtB,
    __hip_bfloat16* __restrict__ qkvB,
    const __hip_bfloat16* __restrict__ WsB, const __hip_bfloat16* __restrict__ neB,
    __hip_bfloat16* __restrict__ WsneK,
    const __hip_bfloat16* __restrict__ n2B, const __hip_bfloat16* __restrict__ projT,
    __hip_bfloat16* __restrict__ Pb)
{
    __shared__ short lds[24576];   // 48 KB: 3x(64+64)x64
    int blk = blockIdx.x;
    if (blk < 384) {
        gemm_dev<64, 64, 2, 2, 5, 1>(lds, catB, 1024, 0, qkvT, D_, 0, bqkv,
                                     (const float*)VtB, qkvB, 1536, 0, D_,
                                     (blk / 24) * 64, (blk % 24) * 64, 0);
    } else if (blk < 400) {
        gemm_dev<64, 64, 2, 2, 1, 1>(lds, WsB, D_, 0, neB, D_, 0, nullptr, nullptr,
                                     WsneK, N_, 0, D_, (blk - 384) * 64, 0, 0);
    } else {
        int local = blk - 400;
        gemm_dev<64, 64, 2, 2, 8, 1>(lds, n2B, D_, 0, projT, D_, (long)R_ * D_,
                                     nullptr, nullptr, Pb, NB_ * R_, R_, D_,
                                     (local & 15) * 64, 0, local >> 4);
    }
}

// ------------------------------------------------------------- flash attention
__global__ __launch_bounds__(256) void attn_mfma(
    const __hip_bfloat16* __restrict__ qkv,
    const __hip_bfloat16* __restrict__ vt,
    __hip_bfloat16* __restrict__ catB)
{
    __shared__ short pbuf[4][16][72];
    const int tid = threadIdx.x;
    const int w = tid >> 6, lane = tid & 63;
    const int g = lane >> 4, ql = lane & 15;
    const int h = blockIdx.y, b = blockIdx.z;
    const int qbase = blockIdx.x * 64 + w * 16;

    const long qrow = ((long)(b * S_ + qbase + ql)) * 1536 + h * DH_;
    bhalf8 qa0 = *(const bhalf8*)(qkv + qrow + g * 8);
    bhalf8 qa1 = *(const bhalf8*)(qkv + qrow + 32 + g * 8);
    const __hip_bfloat16* kB = qkv + 512;
    const __hip_bfloat16* vbase = vt + ((long)(b * H_ + h)) * DH_ * S_;

    floatx4 o[4] = {};
    float m = -INFINITY, ls = 0.f;
    const float SC = 0.125f * 1.44269504088896f;
    const int nblk = blockIdx.x + 1;

    for (int kvb = 0; kvb < nblk; kvb++) {
        const int kb0 = kvb * 64;
        floatx4 st[4];
        #pragma unroll
        for (int t = 0; t < 4; t++) {
            long krow = ((long)(b * S_ + kb0 + t * 16 + ql)) * 1536 + h * DH_;
            bhalf8 ka0 = *(const bhalf8*)(kB + krow + g * 8);
            bhalf8 ka1 = *(const bhalf8*)(kB + krow + 32 + g * 8);
            floatx4 z = {};
            z = __builtin_amdgcn_mfma_f32_16x16x32_bf16(ka0, qa0, z, 0, 0, 0);
            z = __builtin_amdgcn_mfma_f32_16x16x32_bf16(ka1, qa1, z, 0, 0, 0);
            st[t] = z;
        }
        const int q = qbase + ql;
        float p[4][4];
        float m4 = -INFINITY;
        #pragma unroll
        for (int t = 0; t < 4; t++)
            #pragma unroll
            for (int i = 0; i < 4; i++) {
                int kv = kb0 + t * 16 + g * 4 + i;
                float v = (kv <= q) ? st[t][i] * SC : -INFINITY;
                p[t][i] = v; m4 = fmaxf(m4, v);
            }
        m4 = fmaxf(m4, __shfl_xor(m4, 16));
        m4 = fmaxf(m4, __shfl_xor(m4, 32));
        float mnew = fmaxf(m, m4);
        float corr = exp2f(m - mnew);
        m = mnew;
        float lsum = 0.f;
        #pragma unroll
        for (int t = 0; t < 4; t++)
            #pragma unroll
            for (int i = 0; i < 4; i++) {
                float e = exp2f(p[t][i] - mnew);
                p[t][i] = e; lsum += e;
            }
        lsum += __shfl_xor(lsum, 16);
        lsum += __shfl_xor(lsum, 32);
        ls = ls * corr + lsum;
        unsigned* prow = (unsigned*)&pbuf[w][ql][0];
        #pragma unroll
        for (int t = 0; t < 4; t++) {
            prow[t * 8 + g * 2]     = pk2(p[t][0], p[t][1]);
            prow[t * 8 + g * 2 + 1] = pk2(p[t][2], p[t][3]);
        }
        #pragma unroll
        for (int i = 0; i < 4; i++) {
            float c = __shfl(corr, g * 4 + i);
            #pragma unroll
            for (int dt = 0; dt < 4; dt++) o[dt][i] *= c;
        }
        __syncthreads();
        #pragma unroll
        for (int ks = 0; ks < 2; ks++) {
            bhalf8 pa = *(const bhalf8*)&pbuf[w][ql][ks * 32 + g * 8];
            #pragma unroll
            for (int dt = 0; dt < 4; dt++) {
                bhalf8 vb = *(const bhalf8*)(vbase + (long)(dt * 16 + ql) * S_ + kb0 + ks * 32 + g * 8);
                o[dt] = __builtin_amdgcn_mfma_f32_16x16x32_bf16(pa, vb, o[dt], 0, 0, 0);
            }
        }
        __syncthreads();
    }
    const float inv = 1.f / ls;
    #pragma unroll
    for (int i = 0; i < 4; i++) {
        float iv = __shfl(inv, g * 4 + i);
        int trow = b * S_ + qbase + g * 4 + i;
        #pragma unroll
        for (int dt = 0; dt < 4; dt++)
            catB[(long)trow * 1024 + 512 + h * DH_ + dt * 16 + ql] =
                __float2bfloat16(o[dt][i] * iv);
    }
}

// ------------------------------------------------------------- merged prologue
__device__ __forceinline__ void tcvt_dev(const float* in, int ldn, long sIn,
                                         __hip_bfloat16* out, int ldk, long sOut,
                                         int bx, int by, int bz, float (*tsh)[33]) {
    in  += (long)bz * sIn;
    out += (long)bz * sOut;
    int k0 = by * 32, n0 = bx * 32;
    int tx = threadIdx.x & 31, ty = threadIdx.x >> 5;
    #pragma unroll
    for (int r = 0; r < 4; r++) tsh[ty * 4 + r][tx] = in[(long)(k0 + ty * 4 + r) * ldn + n0 + tx];
    __syncthreads();
    #pragma unroll
    for (int r = 0; r < 4; r++)
        out[(long)(n0 + ty * 4 + r) * ldk + k0 + tx] = __float2bfloat16(tsh[tx][ty * 4 + r]);
}

__device__ __forceinline__ void cvt8(const float* in, __hip_bfloat16* out, long i) {
    float4 v0 = *(const float4*)(in + i);
    float4 v1 = *(const float4*)(in + i + 4);
    uint4 pkv = make_uint4(pk2(v0.x, v0.y), pk2(v0.z, v0.w),
                           pk2(v1.x, v1.y), pk2(v1.z, v1.w));
    *(uint4*)(out + i) = pkv;
}

__global__ __launch_bounds__(256) void prologue_kernel(
    const float* __restrict__ temb, __hip_bfloat16* __restrict__ tembB,
    const float* __restrict__ basisA, __hip_bfloat16* __restrict__ projT,
    __hip_bfloat16* __restrict__ deltaT,
    const float* __restrict__ bq, const float* __restrict__ bk,
    const float* __restrict__ bv, float* __restrict__ bqkv,
    const float* __restrict__ Wq, const float* __restrict__ Wk,
    const float* __restrict__ Wv, __hip_bfloat16* __restrict__ qkvT,
    const float* __restrict__ Wup, __hip_bfloat16* __restrict__ WupT,
    const float* __restrict__ Wdn, __hip_bfloat16* __restrict__ WdnT,
    const float* __restrict__ Ws, __hip_bfloat16* __restrict__ WsB,
    const int* __restrict__ ids, const float* __restrict__ pemb,
    float* __restrict__ x)
{
    __shared__ float tsh[32][33];
    const int blk = blockIdx.x, tid = threadIdx.x;
    if (blk < 8000) {
        cvt8(temb, tembB, ((long)blk * 256 + tid) * 8);
    } else if (blk < 12096) {
        long i = (long)(blk - 8000) * 256 + tid;
        int r = i & 63; int d = (i >> 6) & 511; int n = i >> 15;
        __hip_bfloat16 v = __float2bfloat16(basisA[i]);
        projT[((long)n * R_ + r) * D_ + d] = v;
        deltaT[(long)d * (NB_ * R_) + n * R_ + r] = v;
    } else if (blk < 12120) {
        int i = (blk - 12096) * 256 + tid;
        int l = i / 1536, j = i % 1536;
        float v = (j < 512) ? bq[l * 512 + j] : (j < 1024) ? bk[l * 512 + j - 512]
                                                           : bv[l * 512 + j - 1024];
        bqkv[i] = v;
    } else if (blk < 13144) {
        int lin = blk - 12120;
        tcvt_dev(Wq, D_, (long)D_ * D_, qkvT, D_, (long)1536 * D_,
                 lin & 15, (lin >> 4) & 15, lin >> 8, tsh);
    } else if (blk < 14168) {
        int lin = blk - 13144;
        tcvt_dev(Wk, D_, (long)D_ * D_, qkvT + 512 * 512, D_, (long)1536 * D_,
                 lin & 15, (lin >> 4) & 15, lin >> 8, tsh);
    } else if (blk < 15192) {
        int lin = blk - 14168;
        tcvt_dev(Wv, D_, (long)D_ * D_, qkvT + 1024 * 512, D_, (long)1536 * D_,
                 lin & 15, (lin >> 4) & 15, lin >> 8, tsh);
    } else if (blk < 19288) {
        int lin = blk - 15192;
        tcvt_dev(Wup, DFF_, (long)D_ * DFF_, WupT, D_, (long)D_ * DFF_,
                 lin & 63, (lin >> 6) & 15, lin >> 10, tsh);
    } else if (blk < 23384) {
        int lin = blk - 19288;
        tcvt_dev(Wdn, D_, (long)DFF_ * D_, WdnT, DFF_, (long)DFF_ * D_,
                 lin & 15, (lin >> 4) & 63, lin >> 10, tsh);
    } else if (blk < 24408) {
        cvt8(Ws, WsB, ((long)(blk - 23384) * 256 + tid) * 8);
    } else {
        int t = blk - 24408;
        int s = t % S_;
        int id = ids[t];
        for (int d = tid; d < D_; d += 256)
            x[(long)t * D_ + d] = temb[(long)id * D_ + d] + pemb[(long)s * D_ + d];
    }
}

// ------------------------------------------------------------- wave-per-row LN
__device__ __forceinline__ float wave_sum(float v) {
    #pragma unroll
    for (int off = 1; off < 64; off <<= 1) v += __shfl_xor(v, off);
    return v;
}

__device__ __forceinline__ void ln_wave(const float* __restrict__ row,
                                        const float* __restrict__ g,
                                        const float* __restrict__ b,
                                        float* __restrict__ outf,
                                        __hip_bfloat16* __restrict__ outb,
                                        int ldo, long t) {
    int lane = threadIdx.x & 63;
    float4 a0 = *(const float4*)(row + lane * 8);
    float4 a1 = *(const float4*)(row + lane * 8 + 4);
    float v[8] = {a0.x, a0.y, a0.z, a0.w, a1.x, a1.y, a1.z, a1.w};
    float s = 0.f;
    #pragma unroll
    for (int j = 0; j < 8; j++) s += v[j];
    float mean = wave_sum(s) * (1.0f / D_);
    float vs = 0.f;
    #pragma unroll
    for (int j = 0; j < 8; j++) { v[j] -= mean; vs += v[j] * v[j]; }
    float rstd = rsqrtf(wave_sum(vs) * (1.0f / D_) + 1e-5f);
    float4 g0 = *(const float4*)(g + lane * 8), g1 = *(const float4*)(g + lane * 8 + 4);
    float4 b0 = *(const float4*)(b + lane * 8), b1 = *(const float4*)(b + lane * 8 + 4);
    float gg[8] = {g0.x, g0.y, g0.z, g0.w, g1.x, g1.y, g1.z, g1.w};
    float bb[8] = {b0.x, b0.y, b0.z, b0.w, b1.x, b1.y, b1.z, b1.w};
    float o[8];
    #pragma unroll
    for (int j = 0; j < 8; j++) o[j] = v[j] * rstd * gg[j] + bb[j];
    if (outf) {
        *(float4*)(outf + t * D_ + lane * 8)     = make_float4(o[0], o[1], o[2], o[3]);
        *(float4*)(outf + t * D_ + lane * 8 + 4) = make_float4(o[4], o[5], o[6], o[7]);
    }
    uint4 pkv = make_uint4(pk2(o[0], o[1]), pk2(o[2], o[3]), pk2(o[4], o[5]), pk2(o[6], o[7]));
    *(uint4*)(outb + (long)t * ldo + lane * 8) = pkv;
}

// blocks 0-255: ln1 (4 rows) -> catB; 256-511: ln2 -> buf1+n2B; 512-575: ne
__global__ __launch_bounds__(256) void prep_kernel(
    const float* __restrict__ x,
    const float* __restrict__ ln1g, const float* __restrict__ ln1b,
    const float* __restrict__ ln2g, const float* __restrict__ ln2b,
    const float* __restrict__ rec, const float* __restrict__ bemb,
    const float* __restrict__ bs,
    __hip_bfloat16* __restrict__ catB, float* __restrict__ buf1,
    __hip_bfloat16* __restrict__ n2B,
    __hip_bfloat16* __restrict__ neb, float* __restrict__ sel,
    float* __restrict__ bsne)
{
    int blk = blockIdx.x, tid = threadIdx.x, w = tid >> 6;
    if (blk < 256) {
        long t = blk * 4 + w;
        ln_wave(x + t * D_, ln1g, ln1b, nullptr, catB, 1024, t);
    } else if (blk < 512) {
        long t = (blk - 256) * 4 + w;
        ln_wave(x + t * D_, ln2g, ln2b, buf1, n2B, 512, t);
    } else {
        __shared__ float red[256];
        __shared__ float wsm[NB_];
        int n = blk - 512;
        if (tid == 0) {
            float mx = -1e30f;
            for (int i = 0; i < NB_; i++) mx = fmaxf(mx, rec[n * NB_ + i]);
            float sm = 0.f;
            for (int i = 0; i < NB_; i++) { float e = expf(rec[n * NB_ + i] - mx); wsm[i] = e; sm += e; }
            float inv = 1.f / sm;
            for (int i = 0; i < NB_; i++) wsm[i] *= inv;
        }
        __syncthreads();
        if (tid < NB_) sel[n * NB_ + tid] = wsm[tid];
        float part = 0.f;
        for (int d = tid; d < D_; d += 256) {
            float acc = 0.f;
            #pragma unroll
            for (int nb = 0; nb < NB_; nb++) acc += wsm[nb] * bemb[nb * D_ + d];
            neb[(long)n * D_ + d] = __float2bfloat16(acc);
            part += bs[d] * acc;
        }
        red[tid] = part; __syncthreads();
        for (int off = 128; off; off >>= 1) { if (tid < off) red[tid] += red[tid + off]; __syncthreads(); }
        if (tid == 0) bsne[n] = red[0];
    }
}

// ------------------------------------------------------------- final LN (4 rows/block)
__global__ __launch_bounds__(256) void ln_kernel(const float* __restrict__ in,
                                                 const float* __restrict__ g,
                                                 const float* __restrict__ b,
                                                 __hip_bfloat16* __restrict__ outb) {
    long t = blockIdx.x * 4 + (threadIdx.x >> 6);
    ln_wave(in + t * D_, g, b, nullptr, outb, 512, t);
}

// ------------------------------- scores + route + hg (one block per token)
__global__ __launch_bounds__(256) void route_hg(
    const __hip_bfloat16* __restrict__ catB, const __hip_bfloat16* __restrict__ WsneK,
    const float* __restrict__ bsne, const float* __restrict__ sel,
    const __hip_bfloat16* __restrict__ Pb, __hip_bfloat16* __restrict__ g)
{
    int t = blockIdx.x, tid = threadIdx.x;
    __shared__ float catf[1024];
    __shared__ float part[4][64];
    __shared__ float trl[32];
    __shared__ float hl[64];
    {
        short4 vv = *(const short4*)(catB + (long)t * 1024 + tid * 4);
        catf[tid * 4 + 0] = __bfloat162float(*(__hip_bfloat16*)&vv.x);
        catf[tid * 4 + 1] = __bfloat162float(*(__hip_bfloat16*)&vv.y);
        catf[tid * 4 + 2] = __bfloat162float(*(__hip_bfloat16*)&vv.z);
        catf[tid * 4 + 3] = __bfloat162float(*(__hip_bfloat16*)&vv.w);
    }
    __syncthreads();
    int n = tid & 63, q = tid >> 6;
    {
        const __hip_bfloat16* wp = WsneK + (long)q * 256 * 64 + n;
        const float* cf = catf + q * 256;
        float a0 = 0.f, a1 = 0.f, a2 = 0.f, a3 = 0.f;
        #pragma unroll 16
        for (int j = 0; j < 256; j += 4) {
            a0 = fmaf(cf[j],     __bfloat162float(wp[(j)     * 64]), a0);
            a1 = fmaf(cf[j + 1], __bfloat162float(wp[(j + 1) * 64]), a1);
            a2 = fmaf(cf[j + 2], __bfloat162float(wp[(j + 2) * 64]), a2);
            a3 = fmaf(cf[j + 3], __bfloat162float(wp[(j + 3) * 64]), a3);
        }
        part[q][n] = (a0 + a1) + (a2 + a3);
    }
    __syncthreads();
    if (tid < 64) {
        int lane = tid;
        float myval = part[0][lane] + part[1][lane] + part[2][lane] + part[3][lane] + bsne[lane];
        float topv[K_]; int topi[K_];
        #pragma unroll
        for (int kk = 0; kk < K_; kk++) {
            float v = myval; int idx = lane;
            #pragma unroll
            for (int off = 32; off; off >>= 1) {
                float ov = __shfl_down(v, off);
                int oi = __shfl_down(idx, off);
                if (ov > v || (ov == v && oi < idx)) { v = ov; idx = oi; }
            }
            v = __shfl(v, 0); idx = __shfl(idx, 0);
            topv[kk] = v; topi[kk] = idx;
            if (lane == idx) myval = -INFINITY;
        }
        float mx = topv[0];
        float wgt[K_], sum = 0.f;
        #pragma unroll
        for (int kk = 0; kk < K_; kk++) { wgt[kk] = expf(topv[kk] - mx); sum += wgt[kk]; }
        float inv = 1.f / sum;
        if (lane < NB_) {
            float a = 0.f;
            #pragma unroll
            for (int kk = 0; kk < K_; kk++) a += wgt[kk] * inv * sel[topi[kk] * NB_ + lane];
            trl[lane] = a;
        }
    }
    __syncthreads();
    if (tid < 64) {
        float acc = 0.f;
        const __hip_bfloat16* p = Pb + (long)t * 2048 + tid;
        #pragma unroll
        for (int nn = 0; nn < 32; nn++) acc += trl[nn] * __bfloat162float(p[nn * 64]);
        hl[tid] = acc;
    }
    __syncthreads();
    #pragma unroll
    for (int j = 0; j < 8; j++) {
        int idx = tid * 8 + j;
        int nn = idx >> 6, r = idx & 63;
        g[(long)t * 2048 + idx] = __float2bfloat16(trl[nn] * hl[r]);
    }
}

// ------------------------------------------------------------- launch
extern "C" void kernel_launch(void* const* d_in, const int* in_sizes, int n_in,
                              void* d_out, int out_size, void* d_ws, size_t ws_size,
                              hipStream_t stream) {
    const int*   ids    = (const int*)d_in[0];
    const float* temb   = (const float*)d_in[1];
    const float* pemb   = (const float*)d_in[2];
    const float* basisA = (const float*)d_in[3];
    const float* bemb   = (const float*)d_in[4];
    const float* recipe = (const float*)d_in[5];
    const float* Wq = (const float*)d_in[6],  *bq = (const float*)d_in[7];
    const float* Wk = (const float*)d_in[8],  *bk = (const float*)d_in[9];
    const float* Wv = (const float*)d_in[10], *bv = (const float*)d_in[11];
    const float* Ws = (const float*)d_in[12], *bs = (const float*)d_in[13];
    const float* Wup = (const float*)d_in[14], *bup = (const float*)d_in[15];
    const float* Wdn = (const float*)d_in[16], *bdn = (const float*)d_in[17];
    const float* ln1g = (const float*)d_in[18], *ln1b = (const float*)d_in[19];
    const float* ln2g = (const float*)d_in[20], *ln2b = (const float*)d_in[21];
    const float* alpha = (const float*)d_in[22];
    const float* lnfg = (const float*)d_in[23], *lnfb = (const float*)d_in[24];
    float* out = (float*)d_out;
    float* W = (float*)d_ws;

    // fp32 arena (float offsets)
    float* x    = W + 0;          // 524288
    float* buf1 = W + 524288;     // n2 f32 (xf input)
    float* bsne = W + 1114112;    // 64
    float* sel  = W + 1212416;    // 2048
    float* bqkv = W + 3835904;    // 6144
    // bf16 arena
    __hip_bfloat16* SB = (__hip_bfloat16*)(W + 3844096);
    __hip_bfloat16* tembB  = SB + 0;          // 16384000
    __hip_bfloat16* qkvT   = SB + 16384000;   // 3145728
    __hip_bfloat16* WsB    = SB + 19529728;   // 2097152
    __hip_bfloat16* WupT   = SB + 21626880;   // 4194304
    __hip_bfloat16* WdnT   = SB + 25821184;   // 4194304
    __hip_bfloat16* projT  = SB + 30015488;   // 1048576
    __hip_bfloat16* deltaT = SB + 31064064;   // 1048576
    __hip_bfloat16* neB    = SB + 32112640;   // 32768
    __hip_bfloat16* catB   = SB + 32145408;   // 1048576
    __hip_bfloat16* WsneK  = SB + 33193984;   // 65536 ([1024][64])
    __hip_bfloat16* n2B    = SB + 33718272;   // 524288
    __hip_bfloat16* xfB    = SB + 34242560;   // 524288
    __hip_bfloat16* gB     = SB + 34766848;   // 2097152
    __hip_bfloat16* ffhB   = SB + 36864000;   // 2097152
    __hip_bfloat16* qkvB   = SB + 38961152;   // 1572864
    __hip_bfloat16* VtB    = SB + 40534016;   // 524288
    __hip_bfloat16* Pb     = SB + 41058304;   // 2097152 ([1024][2048])

    dim3 blk(256);
    prologue_kernel<<<25432, blk, 0, stream>>>(
        temb, tembB, basisA, projT, deltaT, bq, bk, bv, bqkv,
        Wq, Wk, Wv, qkvT, Wup, WupT, Wdn, WdnT, Ws, WsB, ids, pemb, x);

    for (int l = 0; l < L_; l++) {
        prep_kernel<<<576, blk, 0, stream>>>(
            x, ln1g + l * D_, ln1b + l * D_, ln2g + l * D_, ln2b + l * D_,
            recipe + (long)l * N_ * NB_, bemb, bs + l * D_,
            catB, buf1, n2B, neB, sel, bsne);
        // QKV + Wsne + proj, all 64x64 PIPE1, one dispatch
        mega_gemm<<<912, blk, 0, stream>>>(
            catB, qkvT + (long)l * 1536 * 512, bqkv + l * 1536, VtB, qkvB,
            WsB + (long)l * 1024 * 512, neB, WsneK, n2B, projT, Pb);
        attn_mfma<<<dim3(8, H_, B_), blk, 0, stream>>>(qkvB, VtB, catB);
        // scores + top-k route + h/g (merged)
        route_hg<<<T_, blk, 0, stream>>>(catB, WsneK, bsne, sel, Pb, gB);
        // delta GEMM + fused xf (3-buf pipeline)
        gemm_mfma<64, 64, 2, 2, 3, 0, 1><<<dim3(8, 16), blk, 0, stream>>>(
            gB, NB_ * R_, 0, deltaT, NB_ * R_, 0, alpha + l, buf1,
            xfB, D_, 0, NB_ * R_);
        // FFN up (+gelu, 3-buf pipeline)
        gemm_mfma<64, 64, 2, 2, 2, 0, 1><<<dim3(32, 16), blk, 0, stream>>>(
            xfB, D_, 0, WupT + (long)l * D_ * DFF_, D_, 0, bup + l * DFF_, nullptr,
            ffhB, DFF_, 0, D_);
        // FFN down, split-K=2, fused residual (atomic, 3-buf pipeline)
        gemm_mfma<64, 64, 2, 2, 6, 0, 1><<<dim3(8, 16, 2), blk, 0, stream>>>(
            ffhB, DFF_, 1024, WdnT + (long)l * DFF_ * D_, DFF_, 1024, bdn + l * D_, nullptr,
            x, D_, 0, 1024);
    }
    // final LN + tied head (128x64, XCD-bijective, two-half staged f32 stores)
    ln_kernel<<<256, blk, 0, stream>>>(x, lnfg, lnfb, n2B);
    gemm_mfma<128, 64, 2, 2, 7, 1><<<dim3(4032), blk, 0, stream>>>(
        n2B, D_, 0, tembB, D_, 0, nullptr, nullptr, out, V_, 0, D_);
}